// Round 4
// baseline (147.498 us; speedup 1.0000x reference)
//
#include <hip/hip_runtime.h>
#include <cstdint>

#define NTOK 65536
#define DIM 240
#define KP 256
#define NMETA 600

typedef short bf16x8 __attribute__((ext_vector_type(8)));
typedef float f32x16 __attribute__((ext_vector_type(16)));

union U16B { uint4 u; bf16x8 v; };

__device__ __forceinline__ unsigned short f2bf(float x) {
  unsigned int u = __float_as_uint(x);
  u += 0x7fffu + ((u >> 16) & 1u);     // RNE
  return (unsigned short)(u >> 16);
}

// DPP add: v += dpp_move(v); masked-off / out-of-bounds lanes contribute 0.
template<int CTRL, int RMASK>
__device__ __forceinline__ float dppadd(float v) {
  int t = __builtin_amdgcn_update_dpp(0, __float_as_int(v), CTRL, RMASK, 0xf, true);
  return v + __int_as_float(t);
}
// full 64-lane sum accumulated into lane 63 (rocPRIM pattern), VALU-only
__device__ __forceinline__ float wave_sum63(float v) {
  v = dppadd<0x111, 0xf>(v);   // row_shr:1
  v = dppadd<0x112, 0xf>(v);   // row_shr:2
  v = dppadd<0x114, 0xf>(v);   // row_shr:4
  v = dppadd<0x118, 0xf>(v);   // row_shr:8
  v = dppadd<0x142, 0xa>(v);   // row_bcast:15 -> rows 1,3
  v = dppadd<0x143, 0xc>(v);   // row_bcast:31 -> rows 2,3
  return v;                    // lane 63 = total
}

// ---------------- kernel 1: pack expert weights to bf16 [8][256][256], bias fused at k=240
__global__ __launch_bounds__(256) void prep_w(const float* __restrict__ ew,
                                              const float* __restrict__ eb,
                                              unsigned short* __restrict__ Wb) {
  int idx = blockIdx.x * 256 + threadIdx.x;     // 131072 threads, 4 k's each
  int k0 = (idx & 63) << 2;
  int n  = (idx >> 6) & 255;
  int e  = idx >> 14;
  ushort4 v = {0, 0, 0, 0};
  if (n < DIM) {
    float f0 = 0.f, f1 = 0.f, f2 = 0.f, f3 = 0.f;
    const float* wrow = ew + (e * DIM + n) * DIM;
    if (k0 < DIM) { f0 = wrow[k0]; f1 = wrow[k0 + 1]; f2 = wrow[k0 + 2]; f3 = wrow[k0 + 3]; }
    else if (k0 == DIM) { f0 = eb[e * DIM + n]; }   // bias column
    v.x = f2bf(f0); v.y = f2bf(f1); v.z = f2bf(f2); v.w = f2bf(f3);
  }
  *(ushort4*)&Wb[(size_t)idx * 4] = v;
}

// ---------------- kernel 2: gating + weighted bf16 activations xbp2[t][2][256] + pair id/hist
__global__ __launch_bounds__(256) void gating(const float* __restrict__ x,
                                              const float* __restrict__ gw,
                                              const float* __restrict__ gb,
                                              unsigned short* __restrict__ xbp2,
                                              unsigned char* __restrict__ pairid,
                                              int* __restrict__ cnt) {
  __shared__ __align__(16) float gwT[8][DIM];
  __shared__ int hist[64];
  for (int i = threadIdx.x; i < 8 * DIM; i += 256) gwT[i & 7][i >> 3] = gw[i];
  if (threadIdx.x < 64) hist[threadIdx.x] = 0;
  __syncthreads();
  const int lane = threadIdx.x & 63;
  const int wav = (blockIdx.x << 2) + (threadIdx.x >> 6);   // 16384 waves
  const bool act = lane < 60;
  float4 g[8]; float gbv[8];
#pragma unroll
  for (int e = 0; e < 8; ++e) {
    g[e] = act ? *(const float4*)(&gwT[e][lane * 4]) : make_float4(0.f, 0.f, 0.f, 0.f);
    gbv[e] = gb[e];
  }
  for (int t = wav; t < NTOK; t += 16384) {
    float4 xv = act ? *(const float4*)(x + (size_t)t * DIM + lane * 4)
                    : make_float4(0.f, 0.f, 0.f, 0.f);
    float p[8];
#pragma unroll
    for (int e = 0; e < 8; ++e) {
      p[e] = xv.x * g[e].x + xv.y * g[e].y + xv.z * g[e].z + xv.w * g[e].w;
      p[e] = wave_sum63(p[e]);         // VALU-only reduce, total in lane 63
    }
    float wA = 0.f, wB = 0.f;
    if (lane == 63) {
      float l[8];
#pragma unroll
      for (int e = 0; e < 8; ++e) l[e] = p[e] + gbv[e];
      int i1 = 0; float b1 = l[0];
#pragma unroll
      for (int e = 1; e < 8; ++e) if (l[e] > b1) { b1 = l[e]; i1 = e; }
      int i2 = -1; float b2 = -3.0e38f;
#pragma unroll
      for (int e = 0; e < 8; ++e) if (e != i1 && l[e] > b2) { b2 = l[e]; i2 = e; }
      float q = expf(b2 - b1);
      float w1 = 1.f / (1.f + q);                 // weight of argmax i1
      float w2 = q / (1.f + q);                   // weight of runner-up i2
      int ea = (i1 < i2) ? i1 : i2, eb2 = (i1 < i2) ? i2 : i1;
      wA = (i1 < i2) ? w1 : w2;                   // weight of lower-index expert
      wB = (i1 < i2) ? w2 : w1;
      const int pp = ea * 8 + eb2;
      pairid[t] = (unsigned char)pp;
      atomicAdd(&hist[pp], 1);
    }
    wA = __shfl(wA, 63);
    wB = __shfl(wB, 63);
    ushort4 v0 = {0, 0, 0, 0}, v1 = {0, 0, 0, 0};
    if (act) {
      v0.x = f2bf(xv.x * wA); v0.y = f2bf(xv.y * wA); v0.z = f2bf(xv.z * wA); v0.w = f2bf(xv.w * wA);
      v1.x = f2bf(xv.x * wB); v1.y = f2bf(xv.y * wB); v1.z = f2bf(xv.z * wB); v1.w = f2bf(xv.w * wB);
    } else if (lane == 60) { v0.x = f2bf(wA); v1.x = f2bf(wB); }   // weighted bias column
    *(ushort4*)(xbp2 + ((size_t)t * 2 + 0) * KP + lane * 4) = v0;
    *(ushort4*)(xbp2 + ((size_t)t * 2 + 1) * KP + lane * 4) = v1;
  }
  __syncthreads();
  if (threadIdx.x < 64 && hist[threadIdx.x] > 0) atomicAdd(&cnt[threadIdx.x], hist[threadIdx.x]);
}

// ---------------- kernel 3: scan buckets -> cursors + per-tile meta (256-token tiles)
__global__ void scan_k(const int* __restrict__ cnt, int* __restrict__ gcur,
                       int4* __restrict__ meta) {
  __shared__ int sc[64], sstart[64], stile[64], stot;
  const int tid = threadIdx.x;
  sc[tid] = cnt[tid];
  __syncthreads();
  if (tid == 0) {
    int a = 0, ta = 0;
    for (int p = 0; p < 64; ++p) { sstart[p] = a; stile[p] = ta; a += sc[p]; ta += (sc[p] + 255) >> 8; }
    stot = ta;
  }
  __syncthreads();
  gcur[tid] = sstart[tid];
  const int c = sc[tid], e0 = tid >> 3, e1 = tid & 7;
  for (int i = 0; (i << 8) < c; ++i)
    meta[stile[tid] + i] = make_int4(e0, e1, sstart[tid] + (i << 8), min(256, c - (i << 8)));
  for (int j = stot + tid; j < NMETA; j += 64)
    meta[j] = make_int4(0, 0, 0, 0);
}

// ---------------- kernel 4: scatter token indices into pair buckets
__global__ __launch_bounds__(256) void scatter_k(const unsigned char* __restrict__ pairid,
                                                 int* __restrict__ gcur,
                                                 int* __restrict__ perm) {
  __shared__ int lcnt[64], lbase[64];
  const int tid = threadIdx.x;
  if (tid < 64) lcnt[tid] = 0;
  __syncthreads();
  const int t = blockIdx.x * 256 + tid;
  const int p = pairid[t];
  const int rank = atomicAdd(&lcnt[p], 1);
  __syncthreads();
  if (tid < 64 && lcnt[tid] > 0) lbase[tid] = atomicAdd(&gcur[tid], lcnt[tid]);
  __syncthreads();
  perm[lbase[p] + rank] = t;
}

// ---------------- kernel 5: pair-sparse MoE GEMM, 256 tok x 256 col, wave tile 128x64
#define GLDS16(g, l)                                                        \
  __builtin_amdgcn_global_load_lds(                                         \
      (__attribute__((address_space(1))) unsigned int*)(g),                 \
      (__attribute__((address_space(3))) unsigned int*)(l), 16, 0, 0)

__global__ __launch_bounds__(512, 2) void moe_gemm_pair(const unsigned short* __restrict__ xbp2,
                                                        const unsigned short* __restrict__ Wb,
                                                        const int* __restrict__ perm,
                                                        const int4* __restrict__ meta,
                                                        float* __restrict__ out) {
  extern __shared__ __align__(16) char smem[];
  // [0,64K): A dbuf 2x32K   [64K,128K): W dbuf 2x32K   [128K,+1K): ptok
  int* ptok = (int*)(smem + 131072);

  const int4 m = meta[blockIdx.x];
  const int n = m.w;
  if (n == 0) return;
  const int tid = threadIdx.x, lane = tid & 63, wid = tid >> 6;
  const int wr = wid >> 2, wc = wid & 3;         // 2 row-waves x 4 col-waves
  const int l31 = lane & 31, hi = lane >> 5;

  if (tid < 256) ptok[tid] = perm[m.z + (tid < n ? tid : n - 1)];
  __syncthreads();

  // staging: instr (wid,j) covers rows (wid*4+j)*8 + lane>>3, slot (lane&7)*16 (swizzled)
  const int slot = (lane & 7) * 16;
  const int swz = slot ^ (((lane >> 3) & 7) << 4);
  uint aoff[4]; const char* wsrc[4];
#pragma unroll
  for (int j = 0; j < 4; ++j) {
    const int row = (wid * 4 + j) * 8 + (lane >> 3);
    aoff[j] = (uint)ptok[row] * 1024u + (uint)swz;        // xbp2 token-pair row = 1024 B
    wsrc[j] = (const char*)Wb + (size_t)row * 512 + swz;
  }
  char* dA0 = smem + wid * 4096 + lane * 16;
  char* dW0 = smem + 65536 + wid * 4096 + lane * 16;

  // prologue: stage it=0 (pass 0 = expert m.x, kc=0) into buffer 0
#pragma unroll
  for (int j = 0; j < 4; ++j) GLDS16((const char*)xbp2 + aoff[j], dA0 + j * 1024);
#pragma unroll
  for (int j = 0; j < 4; ++j) GLDS16(wsrc[j] + (size_t)m.x * 131072, dW0 + j * 1024);
  __syncthreads();

  f32x16 acc[4][2] = {};

  for (int it = 0; it < 8; ++it) {               // it = pass*4 + kc; pass 0 -> m.x, pass 1 -> m.y
    const int buf = it & 1;
    if (it < 7) {
      const int nx = it + 1;
      const uint akoff = (uint)((nx >> 2) * 512 + (nx & 3) * 128);
      const size_t eoff = (size_t)((nx >> 2) ? m.y : m.x) * 131072;
      const uint wkoff = (uint)((nx & 3) * 128);
      char* da = dA0 + ((buf ^ 1) << 15);
      char* dw = dW0 + ((buf ^ 1) << 15);
#pragma unroll
      for (int j = 0; j < 4; ++j) GLDS16((const char*)xbp2 + aoff[j] + akoff, da + j * 1024);
#pragma unroll
      for (int j = 0; j < 4; ++j) GLDS16(wsrc[j] + eoff + wkoff, dw + j * 1024);
    }
    const char* Ab = smem + (buf << 15);
    const char* Wp = smem + 65536 + (buf << 15);
    const int sxz0 = (l31 & 7) << 4;
#pragma unroll
    for (int ks = 0; ks < 4; ++ks) {
      const int sx = (ks * 32 + (hi << 4)) ^ sxz0;
      U16B a0, a1, a2, a3, b0, b1;
      a0.u = *(const uint4*)(Ab + ((wr * 128 +  0 + l31) << 7) + sx);
      a1.u = *(const uint4*)(Ab + ((wr * 128 + 32 + l31) << 7) + sx);
      a2.u = *(const uint4*)(Ab + ((wr * 128 + 64 + l31) << 7) + sx);
      a3.u = *(const uint4*)(Ab + ((wr * 128 + 96 + l31) << 7) + sx);
      b0.u = *(const uint4*)(Wp + ((wc * 64 +  0 + l31) << 7) + sx);
      b1.u = *(const uint4*)(Wp + ((wc * 64 + 32 + l31) << 7) + sx);
      acc[0][0] = __builtin_amdgcn_mfma_f32_32x32x16_bf16(a0.v, b0.v, acc[0][0], 0, 0, 0);
      acc[0][1] = __builtin_amdgcn_mfma_f32_32x32x16_bf16(a0.v, b1.v, acc[0][1], 0, 0, 0);
      acc[1][0] = __builtin_amdgcn_mfma_f32_32x32x16_bf16(a1.v, b0.v, acc[1][0], 0, 0, 0);
      acc[1][1] = __builtin_amdgcn_mfma_f32_32x32x16_bf16(a1.v, b1.v, acc[1][1], 0, 0, 0);
      acc[2][0] = __builtin_amdgcn_mfma_f32_32x32x16_bf16(a2.v, b0.v, acc[2][0], 0, 0, 0);
      acc[2][1] = __builtin_amdgcn_mfma_f32_32x32x16_bf16(a2.v, b1.v, acc[2][1], 0, 0, 0);
      acc[3][0] = __builtin_amdgcn_mfma_f32_32x32x16_bf16(a3.v, b0.v, acc[3][0], 0, 0, 0);
      acc[3][1] = __builtin_amdgcn_mfma_f32_32x32x16_bf16(a3.v, b1.v, acc[3][1], 0, 0, 0);
    }
    __syncthreads();     // prefetch drained (covered by compute) + bufs released
  }

  // epilogue: out[tok, col] = acc (weights already folded into A)
#pragma unroll
  for (int af = 0; af < 4; ++af) {
#pragma unroll
    for (int bf = 0; bf < 2; ++bf) {
      const int col = wc * 64 + bf * 32 + l31;
      if (col < DIM) {
#pragma unroll
        for (int r = 0; r < 16; ++r) {
          const int rw = wr * 128 + af * 32 + (r & 3) + ((r >> 2) << 3) + (hi << 2);
          if (rw < n) out[(size_t)ptok[rw] * DIM + col] = acc[af][bf][r];
        }
      }
    }
  }
}

extern "C" void kernel_launch(void* const* d_in, const int* in_sizes, int n_in,
                              void* d_out, int out_size, void* d_ws, size_t ws_size,
                              hipStream_t stream) {
  const float* x  = (const float*)d_in[0];
  const float* gw = (const float*)d_in[1];
  const float* gb = (const float*)d_in[2];
  const float* ew = (const float*)d_in[3];
  const float* eb = (const float*)d_in[4];
  float* out = (float*)d_out;

  // workspace layout
  char* ws = (char*)d_ws;
  unsigned short* Wb   = (unsigned short*)ws;                        // 1 MB
  unsigned short* xbp2 = (unsigned short*)(ws + (1u << 20));         // 64 MB
  int*            perm = (int*)(ws + (65u << 20));                   // 256 KB
  unsigned char*  pid  = (unsigned char*)(ws + (65u << 20) + (256u << 10)); // 64 KB
  int*            cnt  = (int*)(ws + (65u << 20) + (320u << 10));    // 256 B
  int*            gcur = (int*)(ws + (65u << 20) + (321u << 10));    // 256 B
  int4*           meta = (int4*)(ws + (65u << 20) + (322u << 10));   // 9.6 KB

  hipFuncSetAttribute((const void*)moe_gemm_pair, hipFuncAttributeMaxDynamicSharedMemorySize, 132096);

  hipMemsetAsync(cnt, 0, 64 * sizeof(int), stream);
  prep_w<<<512, 256, 0, stream>>>(ew, eb, Wb);
  gating<<<4096, 256, 0, stream>>>(x, gw, gb, xbp2, pid, cnt);
  scan_k<<<1, 64, 0, stream>>>(cnt, gcur, meta);
  scatter_k<<<256, 256, 0, stream>>>(pid, gcur, perm);
  moe_gemm_pair<<<NMETA, 512, 132096, stream>>>(xbp2, Wb, perm, meta, out);
}

// Round 5
// 124.758 us; speedup vs baseline: 1.1823x; 1.1823x over previous
//
#include <hip/hip_runtime.h>
#include <cstdint>

#define NTOK 65536
#define DIM 240
#define KP 256
#define NMETA 600
#define NGB 512          // gating/permute blocks (128 tokens each)

typedef short bf16x8 __attribute__((ext_vector_type(8)));
typedef float f32x16 __attribute__((ext_vector_type(16)));

union U16B { uint4 u; bf16x8 v; };

__device__ __forceinline__ unsigned short f2bf(float x) {
  unsigned int u = __float_as_uint(x);
  u += 0x7fffu + ((u >> 16) & 1u);     // RNE
  return (unsigned short)(u >> 16);
}

// ---------------- kernel 1: pack expert weights to bf16 [8][256][256], bias fused at k=240
__global__ __launch_bounds__(256) void prep_w(const float* __restrict__ ew,
                                              const float* __restrict__ eb,
                                              unsigned short* __restrict__ Wb) {
  int idx = blockIdx.x * 256 + threadIdx.x;     // 131072 threads, 4 k's each
  int k0 = (idx & 63) << 2;
  int n  = (idx >> 6) & 255;
  int e  = idx >> 14;
  ushort4 v = {0, 0, 0, 0};
  if (n < DIM) {
    float f0 = 0.f, f1 = 0.f, f2 = 0.f, f3 = 0.f;
    const float* wrow = ew + (e * DIM + n) * DIM;
    if (k0 < DIM) { f0 = wrow[k0]; f1 = wrow[k0 + 1]; f2 = wrow[k0 + 2]; f3 = wrow[k0 + 3]; }
    else if (k0 == DIM) { f0 = eb[e * DIM + n]; }   // bias column
    v.x = f2bf(f0); v.y = f2bf(f1); v.z = f2bf(f2); v.w = f2bf(f3);
  }
  *(ushort4*)&Wb[(size_t)idx * 4] = v;
}

// ---------------- kernel 2: gating — pairid/wpair/per-block hist. NO global atomics.
// 512 blocks x 512 threads; block b owns tokens [b*128, b*128+128), wave handles 16.
__global__ __launch_bounds__(512) void gating(const float* __restrict__ x,
                                              const float* __restrict__ gw,
                                              const float* __restrict__ gb,
                                              unsigned char* __restrict__ pairid,
                                              float2* __restrict__ wpair,
                                              int* __restrict__ hist2d) {
  __shared__ __align__(16) float gwT[8][DIM];
  __shared__ int hist[64];
  for (int i = threadIdx.x; i < 8 * DIM; i += 512) gwT[i & 7][i >> 3] = gw[i];
  if (threadIdx.x < 64) hist[threadIdx.x] = 0;
  __syncthreads();
  const int lane = threadIdx.x & 63;
  const int w = threadIdx.x >> 6;
  const bool act = lane < 60;
  float4 g[8]; float gbv[8];
#pragma unroll
  for (int e = 0; e < 8; ++e) {
    g[e] = act ? *(const float4*)(&gwT[e][lane * 4]) : make_float4(0.f, 0.f, 0.f, 0.f);
    gbv[e] = gb[e];
  }
  const int tbase = blockIdx.x * 128 + w * 16;
  for (int it = 0; it < 16; ++it) {
    const int t = tbase + it;
    float4 xv = act ? *(const float4*)(x + (size_t)t * DIM + lane * 4)
                    : make_float4(0.f, 0.f, 0.f, 0.f);
    float p[8];
#pragma unroll
    for (int e = 0; e < 8; ++e)
      p[e] = xv.x * g[e].x + xv.y * g[e].y + xv.z * g[e].z + xv.w * g[e].w;
#pragma unroll
    for (int m = 1; m < 64; m <<= 1) {
#pragma unroll
      for (int e = 0; e < 8; ++e) p[e] += __shfl_xor(p[e], m, 64);
    }
    float l[8];
#pragma unroll
    for (int e = 0; e < 8; ++e) l[e] = p[e] + gbv[e];
    int i1 = 0; float b1 = l[0];
#pragma unroll
    for (int e = 1; e < 8; ++e) if (l[e] > b1) { b1 = l[e]; i1 = e; }
    int i2 = -1; float b2 = -3.0e38f;
#pragma unroll
    for (int e = 0; e < 8; ++e) if (e != i1 && l[e] > b2) { b2 = l[e]; i2 = e; }
    float q = expf(b2 - b1);
    float w1 = 1.f / (1.f + q);                  // weight of argmax
    float w2 = q / (1.f + q);                    // weight of runner-up
    if (lane == 0) {
      const int ea = (i1 < i2) ? i1 : i2, eb2 = (i1 < i2) ? i2 : i1;
      const float wa = (i1 < i2) ? w1 : w2, wb2 = (i1 < i2) ? w2 : w1;
      const int pp = ea * 8 + eb2;
      pairid[t] = (unsigned char)pp;
      wpair[t] = make_float2(wa, wb2);
      atomicAdd(&hist[pp], 1);                   // LDS only
    }
  }
  __syncthreads();
  if (threadIdx.x < 64) hist2d[blockIdx.x * 64 + threadIdx.x] = hist[threadIdx.x];
}

// ---------------- kernel 3: per-pair exclusive scan over 512 block-hists (64 blocks)
__global__ __launch_bounds__(512) void scan1_k(const int* __restrict__ hist2d,
                                               int* __restrict__ lbase2d,
                                               int* __restrict__ cnt) {
  __shared__ int s[NGB];
  const int p = blockIdx.x, tid = threadIdx.x;
  const int v = hist2d[tid * 64 + p];
  s[tid] = v;
  __syncthreads();
  for (int off = 1; off < NGB; off <<= 1) {
    int tv = (tid >= off) ? s[tid - off] : 0;
    __syncthreads();
    s[tid] += tv;
    __syncthreads();
  }
  lbase2d[tid * 64 + p] = s[tid] - v;            // exclusive within pair
  if (tid == NGB - 1) cnt[p] = s[tid];
}

// ---------------- kernel 4: pair starts + tile meta (1 block, 64 threads)
__global__ void scan2_k(const int* __restrict__ cnt, int* __restrict__ start,
                        int4* __restrict__ meta) {
  __shared__ int sc[64], sstart[64], stile[64], stot;
  const int tid = threadIdx.x;
  sc[tid] = cnt[tid];
  __syncthreads();
  if (tid == 0) {
    int a = 0, ta = 0;
    for (int p = 0; p < 64; ++p) { sstart[p] = a; stile[p] = ta; a += sc[p]; ta += (sc[p] + 255) >> 8; }
    stot = ta;
  }
  __syncthreads();
  start[tid] = sstart[tid];
  const int c = sc[tid], e0 = tid >> 3, e1 = tid & 7;
  for (int i = 0; (i << 8) < c; ++i)
    meta[stile[tid] + i] = make_int4(e0, e1, sstart[tid] + (i << 8), min(256, c - (i << 8)));
  for (int j = stot + tid; j < NMETA; j += 64)
    meta[j] = make_int4(0, 0, 0, 0);
}

// ---------------- kernel 5: permute + f32->bf16 pack: xbs[pos][256], wsorted, tokord
__global__ __launch_bounds__(512) void permute_k(const float* __restrict__ x,
                                                 const unsigned char* __restrict__ pairid,
                                                 const float2* __restrict__ wpair,
                                                 const int* __restrict__ start,
                                                 const int* __restrict__ lbase2d,
                                                 unsigned short* __restrict__ xbs,
                                                 float2* __restrict__ wsorted,
                                                 int* __restrict__ tokord) {
  __shared__ int lcnt[64], sp[128];
  const int b = blockIdx.x, tid = threadIdx.x;
  if (tid < 64) lcnt[tid] = 0;
  __syncthreads();
  if (tid < 128) {
    const int t = b * 128 + tid;
    const int p = pairid[t];
    const int rank = atomicAdd(&lcnt[p], 1);     // LDS only; intra-bucket order arbitrary
    const int pos = start[p] + lbase2d[b * 64 + p] + rank;
    sp[tid] = pos;
    wsorted[pos] = wpair[t];
    tokord[pos] = t;
  }
  __syncthreads();
  // copy/convert: 128 rows x 32 granules (granule = 8 bf16 = 16B out, 32B f32 in)
  for (int j = tid; j < 128 * 32; j += 512) {
    const int tl = j >> 5, og = j & 31;
    const size_t src = (size_t)(b * 128 + tl) * DIM + og * 8;
    ushort4 o0 = {0, 0, 0, 0}, o1 = {0, 0, 0, 0};
    if (og < 30) {
      const float4 q0 = *(const float4*)(x + src);
      const float4 q1 = *(const float4*)(x + src + 4);
      o0.x = f2bf(q0.x); o0.y = f2bf(q0.y); o0.z = f2bf(q0.z); o0.w = f2bf(q0.w);
      o1.x = f2bf(q1.x); o1.y = f2bf(q1.y); o1.z = f2bf(q1.z); o1.w = f2bf(q1.w);
    } else if (og == 30) {
      o0.x = 0x3F80;                             // k=240 bias column = 1.0
    }
    unsigned short* dst = xbs + (size_t)sp[tl] * KP + og * 8;
    *(ushort4*)dst = o0;
    *(ushort4*)(dst + 4) = o1;
  }
}

// ---------------- kernel 6: pair-sparse GEMM, 256 tok x 256 col, K=64 dbuf, contiguous A
#define GLDS16(g, l)                                                        \
  __builtin_amdgcn_global_load_lds(                                         \
      (__attribute__((address_space(1))) unsigned int*)(g),                 \
      (__attribute__((address_space(3))) unsigned int*)(l), 16, 0, 0)

// stage a [256 rows][64 k] bf16 chunk (32KB) from a row-major 512B-stride source
__device__ __forceinline__ void stage32k(const char* gbase, char* lds, int tid) {
#pragma unroll
  for (int j = 0; j < 4; ++j) {
    const int o = tid * 16 + j * 8192;
    const int r = o >> 7, bb = o & 127;
    GLDS16(gbase + (size_t)r * 512 + (bb ^ ((r & 7) << 4)), lds + o);
  }
}

__global__ __launch_bounds__(512, 2) void moe_gemm_pair(const unsigned short* __restrict__ xbs,
                                                        const unsigned short* __restrict__ Wb,
                                                        const float2* __restrict__ wsorted,
                                                        const int* __restrict__ tokord,
                                                        const int4* __restrict__ meta,
                                                        float* __restrict__ out) {
  extern __shared__ __align__(16) char smem[];
  // [0,64K): A dbuf 2x32K  [64K,128K): W dbuf 2x32K  [128K..]: ptok[256], wab[256]
  int* ptok = (int*)(smem + 131072);
  float2* wab = (float2*)(smem + 132096);

  const int4 m = meta[blockIdx.x];
  const int n = m.w;
  if (n == 0) return;
  const int tid = threadIdx.x, lane = tid & 63, wid = tid >> 6;
  const int wr = wid >> 2, wc = wid & 3;         // 2 row-waves x 4 col-waves, wave 128x64
  const int l31 = lane & 31, hi = lane >> 5;

  if (tid < 256) {
    ptok[tid] = tokord[m.z + tid];
    const float2 w2 = wsorted[m.z + tid];
    const float wbg = fmaxf(w2.y, 1e-35f);
    wab[tid] = make_float2(w2.x / wbg, wbg);     // (ratio wA/wBg, final scale wBg)
  }

  const char* abase = (const char*)xbs + (size_t)m.z * 512;
  const char* wbase0 = (const char*)Wb + (size_t)m.x * 131072;
  const char* wbase1 = (const char*)Wb + (size_t)m.y * 131072;

  // prologue: it=0 (A kc0, W expert m.x kc0) -> buffer 0
  stage32k(abase, smem, tid);
  stage32k(wbase0, smem + 65536, tid);
  __syncthreads();

  f32x16 acc[4][2] = {};

  for (int it = 0; it < 8; ++it) {               // it = pass*4 + kc; pass0 -> m.x, pass1 -> m.y
    const int buf = it & 1;
    if (it < 7) {
      const int nx = it + 1;
      const int koff = (nx & 3) * 128;
      const char* wb = (nx >> 2) ? wbase1 : wbase0;
      stage32k(abase + koff, smem + ((buf ^ 1) << 15), tid);
      stage32k(wb + koff, smem + 65536 + ((buf ^ 1) << 15), tid);
    }
    if (it == 4) {                               // acc = P_A complete -> scale by wA/wBg
#pragma unroll
      for (int af = 0; af < 4; ++af) {
#pragma unroll
        for (int r = 0; r < 16; ++r) {
          const int rw = wr * 128 + af * 32 + (r & 3) + ((r >> 2) << 3) + (hi << 2);
          const float s = wab[rw].x;
          acc[af][0][r] *= s;
          acc[af][1][r] *= s;
        }
      }
    }
    const char* Ab = smem + (buf << 15);
    const char* Wp = smem + 65536 + (buf << 15);
    const int sxz0 = (l31 & 7) << 4;
#pragma unroll
    for (int ks = 0; ks < 4; ++ks) {
      const int sx = (ks * 32 + (hi << 4)) ^ sxz0;
      U16B a0, a1, a2, a3, b0, b1;
      a0.u = *(const uint4*)(Ab + ((wr * 128 +  0 + l31) << 7) + sx);
      a1.u = *(const uint4*)(Ab + ((wr * 128 + 32 + l31) << 7) + sx);
      a2.u = *(const uint4*)(Ab + ((wr * 128 + 64 + l31) << 7) + sx);
      a3.u = *(const uint4*)(Ab + ((wr * 128 + 96 + l31) << 7) + sx);
      b0.u = *(const uint4*)(Wp + ((wc * 64 +  0 + l31) << 7) + sx);
      b1.u = *(const uint4*)(Wp + ((wc * 64 + 32 + l31) << 7) + sx);
      acc[0][0] = __builtin_amdgcn_mfma_f32_32x32x16_bf16(a0.v, b0.v, acc[0][0], 0, 0, 0);
      acc[0][1] = __builtin_amdgcn_mfma_f32_32x32x16_bf16(a0.v, b1.v, acc[0][1], 0, 0, 0);
      acc[1][0] = __builtin_amdgcn_mfma_f32_32x32x16_bf16(a1.v, b0.v, acc[1][0], 0, 0, 0);
      acc[1][1] = __builtin_amdgcn_mfma_f32_32x32x16_bf16(a1.v, b1.v, acc[1][1], 0, 0, 0);
      acc[2][0] = __builtin_amdgcn_mfma_f32_32x32x16_bf16(a2.v, b0.v, acc[2][0], 0, 0, 0);
      acc[2][1] = __builtin_amdgcn_mfma_f32_32x32x16_bf16(a2.v, b1.v, acc[2][1], 0, 0, 0);
      acc[3][0] = __builtin_amdgcn_mfma_f32_32x32x16_bf16(a3.v, b0.v, acc[3][0], 0, 0, 0);
      acc[3][1] = __builtin_amdgcn_mfma_f32_32x32x16_bf16(a3.v, b1.v, acc[3][1], 0, 0, 0);
    }
    __syncthreads();       // prefetch drained (covered by compute) + bufs released
  }

  // epilogue: out[tok, col] = wBg * acc
#pragma unroll
  for (int af = 0; af < 4; ++af) {
#pragma unroll
    for (int bf = 0; bf < 2; ++bf) {
      const int col = wc * 64 + bf * 32 + l31;
      if (col < DIM) {
#pragma unroll
        for (int r = 0; r < 16; ++r) {
          const int rw = wr * 128 + af * 32 + (r & 3) + ((r >> 2) << 3) + (hi << 2);
          if (rw < n) out[(size_t)ptok[rw] * DIM + col] = wab[rw].y * acc[af][bf][r];
        }
      }
    }
  }
}

extern "C" void kernel_launch(void* const* d_in, const int* in_sizes, int n_in,
                              void* d_out, int out_size, void* d_ws, size_t ws_size,
                              hipStream_t stream) {
  const float* x  = (const float*)d_in[0];
  const float* gw = (const float*)d_in[1];
  const float* gb = (const float*)d_in[2];
  const float* ew = (const float*)d_in[3];
  const float* eb = (const float*)d_in[4];
  float* out = (float*)d_out;

  // workspace layout (~36.4 MB total)
  char* ws = (char*)d_ws;
  unsigned short* Wb   = (unsigned short*)ws;                          // 1 MB
  unsigned short* xbs  = (unsigned short*)(ws + 1048576);              // (65536+256)*512B
  float2*         wpr  = (float2*)(ws + 34734080);                     // 512 KB
  float2*         wsr  = (float2*)(ws + 35258368);                     // (65536+256)*8B
  int*            tord = (int*)(ws + 35784704);                        // (65536+256)*4B
  unsigned char*  pid  = (unsigned char*)(ws + 36047872);              // 64 KB
  int*            h2d  = (int*)(ws + 36113408);                        // 128 KB
  int*            lb2d = (int*)(ws + 36244480);                        // 128 KB
  int*            cnt  = (int*)(ws + 36375552);                        // 256 B
  int*            strt = (int*)(ws + 36375808);                        // 256 B
  int4*           meta = (int4*)(ws + 36376064);                       // 9.6 KB

  hipFuncSetAttribute((const void*)moe_gemm_pair, hipFuncAttributeMaxDynamicSharedMemorySize, 134144);

  prep_w<<<512, 256, 0, stream>>>(ew, eb, Wb);
  gating<<<NGB, 512, 0, stream>>>(x, gw, gb, pid, wpr, h2d);
  scan1_k<<<64, NGB, 0, stream>>>(h2d, lb2d, cnt);
  scan2_k<<<1, 64, 0, stream>>>(cnt, strt, meta);
  permute_k<<<NGB, 512, 0, stream>>>(x, pid, wpr, strt, lb2d, xbs, wsr, tord);
  moe_gemm_pair<<<NMETA, 512, 134144, stream>>>(xbs, Wb, wsr, tord, meta, out);
}

// Round 6
// 124.294 us; speedup vs baseline: 1.1867x; 1.0037x over previous
//
#include <hip/hip_runtime.h>
#include <cstdint>

#define NTOK 65536
#define DIM 240
#define KP 256
#define NMETA 600
#define NGB 512          // gating/permute blocks (128 tokens each)

typedef short bf16x8 __attribute__((ext_vector_type(8)));
typedef float f32x16 __attribute__((ext_vector_type(16)));

union U16B { uint4 u; bf16x8 v; };

__device__ __forceinline__ unsigned short f2bf(float x) {
  unsigned int u = __float_as_uint(x);
  u += 0x7fffu + ((u >> 16) & 1u);     // RNE
  return (unsigned short)(u >> 16);
}

// ---------------- kernel 1: pack expert weights to bf16 [8][256][256], bias fused at k=240
__global__ __launch_bounds__(256) void prep_w(const float* __restrict__ ew,
                                              const float* __restrict__ eb,
                                              unsigned short* __restrict__ Wb) {
  int idx = blockIdx.x * 256 + threadIdx.x;     // 131072 threads, 4 k's each
  int k0 = (idx & 63) << 2;
  int n  = (idx >> 6) & 255;
  int e  = idx >> 14;
  ushort4 v = {0, 0, 0, 0};
  if (n < DIM) {
    float f0 = 0.f, f1 = 0.f, f2 = 0.f, f3 = 0.f;
    const float* wrow = ew + (e * DIM + n) * DIM;
    if (k0 < DIM) { f0 = wrow[k0]; f1 = wrow[k0 + 1]; f2 = wrow[k0 + 2]; f3 = wrow[k0 + 3]; }
    else if (k0 == DIM) { f0 = eb[e * DIM + n]; }   // bias column
    v.x = f2bf(f0); v.y = f2bf(f1); v.z = f2bf(f2); v.w = f2bf(f3);
  }
  *(ushort4*)&Wb[(size_t)idx * 4] = v;
}

// ---------------- kernel 2: gating — pairid/wpair/per-block hist. NO global atomics.
__global__ __launch_bounds__(512) void gating(const float* __restrict__ x,
                                              const float* __restrict__ gw,
                                              const float* __restrict__ gb,
                                              unsigned char* __restrict__ pairid,
                                              float2* __restrict__ wpair,
                                              int* __restrict__ hist2d) {
  __shared__ __align__(16) float gwT[8][DIM];
  __shared__ int hist[64];
  for (int i = threadIdx.x; i < 8 * DIM; i += 512) gwT[i & 7][i >> 3] = gw[i];
  if (threadIdx.x < 64) hist[threadIdx.x] = 0;
  __syncthreads();
  const int lane = threadIdx.x & 63;
  const int w = threadIdx.x >> 6;
  const bool act = lane < 60;
  float4 g[8]; float gbv[8];
#pragma unroll
  for (int e = 0; e < 8; ++e) {
    g[e] = act ? *(const float4*)(&gwT[e][lane * 4]) : make_float4(0.f, 0.f, 0.f, 0.f);
    gbv[e] = gb[e];
  }
  const int tbase = blockIdx.x * 128 + w * 16;
  for (int it = 0; it < 16; ++it) {
    const int t = tbase + it;
    float4 xv = act ? *(const float4*)(x + (size_t)t * DIM + lane * 4)
                    : make_float4(0.f, 0.f, 0.f, 0.f);
    float p[8];
#pragma unroll
    for (int e = 0; e < 8; ++e)
      p[e] = xv.x * g[e].x + xv.y * g[e].y + xv.z * g[e].z + xv.w * g[e].w;
#pragma unroll
    for (int m = 1; m < 64; m <<= 1) {
#pragma unroll
      for (int e = 0; e < 8; ++e) p[e] += __shfl_xor(p[e], m, 64);
    }
    float l[8];
#pragma unroll
    for (int e = 0; e < 8; ++e) l[e] = p[e] + gbv[e];
    int i1 = 0; float b1 = l[0];
#pragma unroll
    for (int e = 1; e < 8; ++e) if (l[e] > b1) { b1 = l[e]; i1 = e; }
    int i2 = -1; float b2 = -3.0e38f;
#pragma unroll
    for (int e = 0; e < 8; ++e) if (e != i1 && l[e] > b2) { b2 = l[e]; i2 = e; }
    float q = expf(b2 - b1);
    float w1 = 1.f / (1.f + q);                  // weight of argmax
    float w2 = q / (1.f + q);                    // weight of runner-up
    if (lane == 0) {
      const int ea = (i1 < i2) ? i1 : i2, eb2 = (i1 < i2) ? i2 : i1;
      const float wa = (i1 < i2) ? w1 : w2, wb2 = (i1 < i2) ? w2 : w1;
      const int pp = ea * 8 + eb2;
      pairid[t] = (unsigned char)pp;
      wpair[t] = make_float2(wa, wb2);
      atomicAdd(&hist[pp], 1);                   // LDS only
    }
  }
  __syncthreads();
  if (threadIdx.x < 64) hist2d[blockIdx.x * 64 + threadIdx.x] = hist[threadIdx.x];
}

// ---------------- kernel 3: per-pair exclusive scan over 512 block-hists (64 blocks)
__global__ __launch_bounds__(512) void scan1_k(const int* __restrict__ hist2d,
                                               int* __restrict__ lbase2d,
                                               int* __restrict__ cnt) {
  __shared__ int s[NGB];
  const int p = blockIdx.x, tid = threadIdx.x;
  const int v = hist2d[tid * 64 + p];
  s[tid] = v;
  __syncthreads();
  for (int off = 1; off < NGB; off <<= 1) {
    int tv = (tid >= off) ? s[tid - off] : 0;
    __syncthreads();
    s[tid] += tv;
    __syncthreads();
  }
  lbase2d[tid * 64 + p] = s[tid] - v;            // exclusive within pair
  if (tid == NGB - 1) cnt[p] = s[tid];
}

// ---------------- kernel 4: pair starts + tile meta (1 block, 64 threads)
__global__ void scan2_k(const int* __restrict__ cnt, int* __restrict__ start,
                        int4* __restrict__ meta) {
  __shared__ int sc[64], sstart[64], stile[64], stot;
  const int tid = threadIdx.x;
  sc[tid] = cnt[tid];
  __syncthreads();
  if (tid == 0) {
    int a = 0, ta = 0;
    for (int p = 0; p < 64; ++p) { sstart[p] = a; stile[p] = ta; a += sc[p]; ta += (sc[p] + 255) >> 8; }
    stot = ta;
  }
  __syncthreads();
  start[tid] = sstart[tid];
  const int c = sc[tid], e0 = tid >> 3, e1 = tid & 7;
  for (int i = 0; (i << 8) < c; ++i)
    meta[stile[tid] + i] = make_int4(e0, e1, sstart[tid] + (i << 8), min(256, c - (i << 8)));
  for (int j = stot + tid; j < NMETA; j += 64)
    meta[j] = make_int4(0, 0, 0, 0);
}

// ---------------- kernel 5: permute + f32->bf16 pack: xbs[pos][256], wsorted, tokord
__global__ __launch_bounds__(512) void permute_k(const float* __restrict__ x,
                                                 const unsigned char* __restrict__ pairid,
                                                 const float2* __restrict__ wpair,
                                                 const int* __restrict__ start,
                                                 const int* __restrict__ lbase2d,
                                                 unsigned short* __restrict__ xbs,
                                                 float2* __restrict__ wsorted,
                                                 int* __restrict__ tokord) {
  __shared__ int lcnt[64], sp[128];
  const int b = blockIdx.x, tid = threadIdx.x;
  if (tid < 64) lcnt[tid] = 0;
  __syncthreads();
  if (tid < 128) {
    const int t = b * 128 + tid;
    const int p = pairid[t];
    const int rank = atomicAdd(&lcnt[p], 1);     // LDS only; intra-bucket order arbitrary
    const int pos = start[p] + lbase2d[b * 64 + p] + rank;
    sp[tid] = pos;
    wsorted[pos] = wpair[t];
    tokord[pos] = t;
  }
  __syncthreads();
  // copy/convert: 128 rows x 32 granules (granule = 8 bf16 = 16B out, 32B f32 in)
  for (int j = tid; j < 128 * 32; j += 512) {
    const int tl = j >> 5, og = j & 31;
    const size_t src = (size_t)(b * 128 + tl) * DIM + og * 8;
    ushort4 o0 = {0, 0, 0, 0}, o1 = {0, 0, 0, 0};
    if (og < 30) {
      const float4 q0 = *(const float4*)(x + src);
      const float4 q1 = *(const float4*)(x + src + 4);
      o0.x = f2bf(q0.x); o0.y = f2bf(q0.y); o0.z = f2bf(q0.z); o0.w = f2bf(q0.w);
      o1.x = f2bf(q1.x); o1.y = f2bf(q1.y); o1.z = f2bf(q1.z); o1.w = f2bf(q1.w);
    } else if (og == 30) {
      o0.x = 0x3F80;                             // k=240 bias column = 1.0
    }
    unsigned short* dst = xbs + (size_t)sp[tl] * KP + og * 8;
    *(ushort4*)dst = o0;
    *(ushort4*)(dst + 4) = o1;
  }
}

// ---------------- kernel 6: pair-sparse GEMM, counted-vmcnt pipelined (T3/T4)
#define GLDS16(g, l)                                                        \
  __builtin_amdgcn_global_load_lds(                                         \
      (__attribute__((address_space(1))) unsigned int*)(g),                 \
      (__attribute__((address_space(3))) unsigned int*)(l), 16, 0, 0)

// stage a [256 rows][64 k] bf16 chunk (32KB) from a row-major 512B-stride source
__device__ __forceinline__ void stage32k(const char* gbase, char* lds, int tid) {
#pragma unroll
  for (int j = 0; j < 4; ++j) {
    const int o = tid * 16 + j * 8192;
    const int r = o >> 7, bb = o & 127;
    GLDS16(gbase + (size_t)r * 512 + (bb ^ ((r & 7) << 4)), lds + o);
  }
}

__global__ __launch_bounds__(512, 2) void moe_gemm_pair(const unsigned short* __restrict__ xbs,
                                                        const unsigned short* __restrict__ Wb,
                                                        const float2* __restrict__ wsorted,
                                                        const int* __restrict__ tokord,
                                                        const int4* __restrict__ meta,
                                                        float* __restrict__ out) {
  extern __shared__ __align__(16) char smem[];
  // [0,64K): A dbuf 2x32K  [64K,128K): W dbuf 2x32K  [128K..]: ptok[256], wab[256]
  int* ptok = (int*)(smem + 131072);
  float2* wab = (float2*)(smem + 132096);

  const int4 m = meta[blockIdx.x];
  const int n = m.w;
  if (n == 0) return;
  const int tid = threadIdx.x, lane = tid & 63, wid = tid >> 6;
  const int wr = wid >> 2, wc = wid & 3;         // 2 row-waves x 4 col-waves, wave 128x64
  const int l31 = lane & 31, hi = lane >> 5;

  if (tid < 256) {
    ptok[tid] = tokord[m.z + tid];
    const float2 w2 = wsorted[m.z + tid];
    const float wbg = fmaxf(w2.y, 1e-35f);
    wab[tid] = make_float2(w2.x / wbg, wbg);     // (ratio wA/wBg, final scale wBg)
  }

  const char* abase = (const char*)xbs + (size_t)m.z * 512;
  const char* wbase0 = (const char*)Wb + (size_t)m.x * 131072;
  const char* wbase1 = (const char*)Wb + (size_t)m.y * 131072;

  // prologue: it=0 (A kc0, W expert m.x kc0) -> buffer 0; full drain once.
  stage32k(abase, smem, tid);
  stage32k(wbase0, smem + 65536, tid);
  __syncthreads();

  f32x16 acc[4][2] = {};

  for (int it = 0; it < 8; ++it) {               // it = pass*4 + kc; pass0 -> m.x, pass1 -> m.y
    const int buf = it & 1;
    if (it > 0) {
      // barA: all waves finished reading slot buf^1 last iter -> safe to overwrite
      __builtin_amdgcn_s_barrier();
      __builtin_amdgcn_sched_barrier(0);
    }
    if (it < 7) {
      const int nx = it + 1;
      const int koff = (nx & 3) * 128;
      const char* wb = (nx >> 2) ? wbase1 : wbase0;
      stage32k(abase + koff, smem + ((buf ^ 1) << 15), tid);          // 4 GLDS16
      stage32k(wb + koff, smem + 65536 + ((buf ^ 1) << 15), tid);     // 4 GLDS16
      __builtin_amdgcn_sched_barrier(0);
      // wait only the PREVIOUS iter's 8 loads (this slot's data); keep our 8 in flight
      asm volatile("s_waitcnt vmcnt(8)" ::: "memory");
    } else {
      __builtin_amdgcn_sched_barrier(0);
      asm volatile("s_waitcnt vmcnt(0)" ::: "memory");
    }
    __builtin_amdgcn_sched_barrier(0);
    __builtin_amdgcn_s_barrier();                // barB: slot `buf` ready for all waves
    __builtin_amdgcn_sched_barrier(0);
    if (it == 4) {                               // acc = P_A complete -> scale by wA/wBg
#pragma unroll
      for (int af = 0; af < 4; ++af) {
#pragma unroll
        for (int r = 0; r < 16; ++r) {
          const int rw = wr * 128 + af * 32 + (r & 3) + ((r >> 2) << 3) + (hi << 2);
          const float s = wab[rw].x;
          acc[af][0][r] *= s;
          acc[af][1][r] *= s;
        }
      }
    }
    const char* Ab = smem + (buf << 15);
    const char* Wp = smem + 65536 + (buf << 15);
    const int sxz0 = (l31 & 7) << 4;
#pragma unroll
    for (int ks = 0; ks < 4; ++ks) {
      const int sx = (ks * 32 + (hi << 4)) ^ sxz0;
      U16B a0, a1, a2, a3, b0, b1;
      a0.u = *(const uint4*)(Ab + ((wr * 128 +  0 + l31) << 7) + sx);
      a1.u = *(const uint4*)(Ab + ((wr * 128 + 32 + l31) << 7) + sx);
      a2.u = *(const uint4*)(Ab + ((wr * 128 + 64 + l31) << 7) + sx);
      a3.u = *(const uint4*)(Ab + ((wr * 128 + 96 + l31) << 7) + sx);
      b0.u = *(const uint4*)(Wp + ((wc * 64 +  0 + l31) << 7) + sx);
      b1.u = *(const uint4*)(Wp + ((wc * 64 + 32 + l31) << 7) + sx);
      acc[0][0] = __builtin_amdgcn_mfma_f32_32x32x16_bf16(a0.v, b0.v, acc[0][0], 0, 0, 0);
      acc[0][1] = __builtin_amdgcn_mfma_f32_32x32x16_bf16(a0.v, b1.v, acc[0][1], 0, 0, 0);
      acc[1][0] = __builtin_amdgcn_mfma_f32_32x32x16_bf16(a1.v, b0.v, acc[1][0], 0, 0, 0);
      acc[1][1] = __builtin_amdgcn_mfma_f32_32x32x16_bf16(a1.v, b1.v, acc[1][1], 0, 0, 0);
      acc[2][0] = __builtin_amdgcn_mfma_f32_32x32x16_bf16(a2.v, b0.v, acc[2][0], 0, 0, 0);
      acc[2][1] = __builtin_amdgcn_mfma_f32_32x32x16_bf16(a2.v, b1.v, acc[2][1], 0, 0, 0);
      acc[3][0] = __builtin_amdgcn_mfma_f32_32x32x16_bf16(a3.v, b0.v, acc[3][0], 0, 0, 0);
      acc[3][1] = __builtin_amdgcn_mfma_f32_32x32x16_bf16(a3.v, b1.v, acc[3][1], 0, 0, 0);
    }
    // no drain here: next iter's barA orders readers vs the overwrite
  }

  // epilogue: out[tok, col] = wBg * acc
#pragma unroll
  for (int af = 0; af < 4; ++af) {
#pragma unroll
    for (int bf = 0; bf < 2; ++bf) {
      const int col = wc * 64 + bf * 32 + l31;
      if (col < DIM) {
#pragma unroll
        for (int r = 0; r < 16; ++r) {
          const int rw = wr * 128 + af * 32 + (r & 3) + ((r >> 2) << 3) + (hi << 2);
          if (rw < n) out[(size_t)ptok[rw] * DIM + col] = wab[rw].y * acc[af][bf][r];
        }
      }
    }
  }
}

extern "C" void kernel_launch(void* const* d_in, const int* in_sizes, int n_in,
                              void* d_out, int out_size, void* d_ws, size_t ws_size,
                              hipStream_t stream) {
  const float* x  = (const float*)d_in[0];
  const float* gw = (const float*)d_in[1];
  const float* gb = (const float*)d_in[2];
  const float* ew = (const float*)d_in[3];
  const float* eb = (const float*)d_in[4];
  float* out = (float*)d_out;

  // workspace layout (~36.4 MB total)
  char* ws = (char*)d_ws;
  unsigned short* Wb   = (unsigned short*)ws;                          // 1 MB
  unsigned short* xbs  = (unsigned short*)(ws + 1048576);              // (65536+256)*512B
  float2*         wpr  = (float2*)(ws + 34734080);                     // 512 KB
  float2*         wsr  = (float2*)(ws + 35258368);                     // (65536+256)*8B
  int*            tord = (int*)(ws + 35784704);                        // (65536+256)*4B
  unsigned char*  pid  = (unsigned char*)(ws + 36047872);              // 64 KB
  int*            h2d  = (int*)(ws + 36113408);                        // 128 KB
  int*            lb2d = (int*)(ws + 36244480);                        // 128 KB
  int*            cnt  = (int*)(ws + 36375552);                        // 256 B
  int*            strt = (int*)(ws + 36375808);                        // 256 B
  int4*           meta = (int4*)(ws + 36376064);                       // 9.6 KB

  hipFuncSetAttribute((const void*)moe_gemm_pair, hipFuncAttributeMaxDynamicSharedMemorySize, 134144);

  prep_w<<<512, 256, 0, stream>>>(ew, eb, Wb);
  gating<<<NGB, 512, 0, stream>>>(x, gw, gb, pid, wpr, h2d);
  scan1_k<<<64, NGB, 0, stream>>>(h2d, lb2d, cnt);
  scan2_k<<<1, 64, 0, stream>>>(cnt, strt, meta);
  permute_k<<<NGB, 512, 0, stream>>>(x, pid, wpr, strt, lb2d, xbs, wsr, tord);
  moe_gemm_pair<<<NMETA, 512, 134144, stream>>>(xbs, Wb, wsr, tord, meta, out);
}